// Round 1
// baseline (428.160 us; speedup 1.0000x reference)
//
#include <hip/hip_runtime.h>

#define SEQ   4096
#define CDIM  256
#define NHEAD 4
#define DHEAD 64
#define PSTRIDE 72   // P-buffer row stride (f16): 144 B rows -> 16B-aligned b128 reads

typedef float    f32x4 __attribute__((ext_vector_type(4)));
typedef _Float16 f16x8 __attribute__((ext_vector_type(8)));
typedef _Float16 f16x4 __attribute__((ext_vector_type(4)));

__device__ __forceinline__ f16x8 cvt_frag(const float* __restrict__ p) {
    float4 f0 = *(const float4*)p;
    float4 f1 = *(const float4*)(p + 4);
    f16x8 r;
    r[0]=(_Float16)f0.x; r[1]=(_Float16)f0.y; r[2]=(_Float16)f0.z; r[3]=(_Float16)f0.w;
    r[4]=(_Float16)f1.x; r[5]=(_Float16)f1.y; r[6]=(_Float16)f1.z; r[7]=(_Float16)f1.w;
    return r;
}

// ---------------- Kernel 0: weight fp32->fp16 prep ----------------
__global__ __launch_bounds__(256) void sta_prep(
    const float* __restrict__ qw, const float* __restrict__ kw,
    const float* __restrict__ vw, const float* __restrict__ ow,
    _Float16* __restrict__ w16)
{
    const int mat = blockIdx.y;
    const float* src = (mat == 0) ? qw : (mat == 1) ? kw : (mat == 2) ? vw : ow;
    const int i = (blockIdx.x * 256 + threadIdx.x) * 8;
    *(f16x8*)(w16 + mat * 65536 + i) = cvt_frag(src + i);
}

// ---------------- Kernel 1: QKV projection ----------------
__global__ __launch_bounds__(256) void sta_qkv(
    const float* __restrict__ x, const _Float16* __restrict__ w16,
    const float* __restrict__ qb, const float* __restrict__ kb, const float* __restrict__ vb,
    _Float16* __restrict__ Qo, _Float16* __restrict__ Ko, _Float16* __restrict__ Vo)
{
    const int wave = threadIdx.x >> 6;
    const int lane = threadIdx.x & 63;
    const int l15  = lane & 15;
    const int quad = lane >> 4;
    const int mat  = blockIdx.y;
    const int half = blockIdx.z;
    const int row0 = blockIdx.x * 64 + wave * 16;

    const _Float16* w    = w16 + mat * 65536;
    const float*    bias = (mat == 0) ? qb : (mat == 1) ? kb : vb;

    f16x8 xf[8];
    const float* xrow = x + (row0 + l15) * CDIM + quad * 8;
    #pragma unroll
    for (int ks = 0; ks < 8; ks++) xf[ks] = cvt_frag(xrow + ks * 32);

    #pragma unroll 1
    for (int ct = 0; ct < 8; ct++) {
        const int ctg = half * 8 + ct;
        const _Float16* wr = w + (ctg * 16 + l15) * CDIM + quad * 8;
        f32x4 acc = {0.f, 0.f, 0.f, 0.f};
        if (mat < 2) {
            #pragma unroll
            for (int ks = 0; ks < 8; ks++)
                acc = __builtin_amdgcn_mfma_f32_16x16x32_f16(*(const f16x8*)(wr + ks * 32), xf[ks], acc, 0, 0, 0);
            const float4 bv = *(const float4*)(bias + ctg * 16 + quad * 4);
            const int c0 = ctg * 16 + quad * 4;
            const int h = c0 >> 6, d0 = c0 & 63;
            const int grow = row0 + l15, b = grow >> 12, n = grow & (SEQ - 1);
            const float sc = (mat == 0) ? 0.0625f : 1.0f;
            f16x4 o;
            o[0] = (_Float16)((acc[0] + bv.x) * sc);
            o[1] = (_Float16)((acc[1] + bv.y) * sc);
            o[2] = (_Float16)((acc[2] + bv.z) * sc);
            o[3] = (_Float16)((acc[3] + bv.w) * sc);
            _Float16* dst = ((mat == 0) ? Qo : Ko) + (((b * NHEAD + h) * SEQ + n) * DHEAD + d0);
            *(f16x4*)dst = o;
        } else {
            #pragma unroll
            for (int ks = 0; ks < 8; ks++)
                acc = __builtin_amdgcn_mfma_f32_16x16x32_f16(xf[ks], *(const f16x8*)(wr + ks * 32), acc, 0, 0, 0);
            const int c = ctg * 16 + l15;
            const int h = c >> 6, d = c & 63;
            const float bv = bias[c];
            const int grow0 = row0 + quad * 4, b = grow0 >> 12, n0 = grow0 & (SEQ - 1);
            f16x4 o;
            #pragma unroll
            for (int r = 0; r < 4; r++) o[r] = (_Float16)(acc[r] + bv);
            *(f16x4*)(Vo + (((b * NHEAD + h) * DHEAD + d) * SEQ + n0)) = o;
        }
    }
}

// ---------------- Kernel 2: flash attention, 2-wave blocks, in-block kv split ----------------
// grid (64 q-tiles of 64, 8 bh, 4 kv-splits), 128 thr = 2 waves.
// Each wave owns 64 Q-rows x 8 kv-tiles (half the block's kv range) with a
// wave-private P-buffer (no barriers in the sweep). QK^T operand-swapped:
// S[kv][q] -> packed ds_write_b64 of P; PV reads P back as b128 A-fragments.
// Epilogue: symmetric cross-wave O/denominator exchange through the (dead)
// P-buffers, each wave finishes + stores its 32 owned Q-rows.
__global__ __launch_bounds__(128, 4) void sta_attn(
    const _Float16* __restrict__ Q, const _Float16* __restrict__ K, const _Float16* __restrict__ Vt,
    const float* __restrict__ taup,
    float* __restrict__ Opart, float* __restrict__ lpart)
{
    __shared__ __align__(16) _Float16 pbuf[2 * 64 * PSTRIDE];   // per-wave halves

    const int wave = threadIdx.x >> 6;
    const int lane = threadIdx.x & 63;
    const int l15  = lane & 15;
    const int quad = lane >> 4;
    const int qt = blockIdx.x;   // 0..63
    const int bh = blockIdx.y;   // 0..7
    const int sp = blockIdx.z;   // 0..3
    const float tau_eff = fmaxf(taup[0], 0.0f);

    _Float16* pb = pbuf + wave * (64 * PSTRIDE);   // wave-private P-buffer

    const _Float16* Qb = Q  + bh * SEQ * DHEAD;
    const _Float16* Kb = K  + bh * SEQ * DHEAD;
    const _Float16* Vb = Vt + bh * DHEAD * SEQ;

    const int q0 = qt * 64;

    // Q B-fragments, held for the whole sweep: col=l15 -> q, k=quad*8+j -> d
    f16x8 qf[4][2];
    #pragma unroll
    for (int qb = 0; qb < 4; qb++)
        #pragma unroll
        for (int ks = 0; ks < 2; ks++)
            qf[qb][ks] = *(const f16x8*)(Qb + (q0 + qb * 16 + l15) * DHEAD + ks * 32 + quad * 8);

    f32x4 O[4][4];   // [qb][db]
    #pragma unroll
    for (int qb = 0; qb < 4; qb++)
        #pragma unroll
        for (int db = 0; db < 4; db++) O[qb][db] = (f32x4){0.f, 0.f, 0.f, 0.f};
    float rs[4] = {0.f, 0.f, 0.f, 0.f};   // per-lane denominator partials, q = q0+qb*16+l15

    const int kt0 = sp * 16 + wave * 8;   // this wave's 8 kv-tiles
    #pragma unroll 1
    for (int kt = kt0; kt < kt0 + 8; kt++) {
        const int kv0 = kt * 64;

        // ---- S' = K Q^T (swapped): rows=kv, cols=q. Gate+exp, packed b64 P-writes.
        #pragma unroll
        for (int kb = 0; kb < 4; kb++) {
            const _Float16* kp = Kb + (kv0 + kb * 16 + l15) * DHEAD + quad * 8;
            f16x8 k0 = *(const f16x8*)kp;
            f16x8 k1 = *(const f16x8*)(kp + 32);
            #pragma unroll
            for (int qb = 0; qb < 4; qb++) {
                f32x4 a = {0.f, 0.f, 0.f, 0.f};
                a = __builtin_amdgcn_mfma_f32_16x16x32_f16(k0, qf[qb][0], a, 0, 0, 0);
                a = __builtin_amdgcn_mfma_f32_16x16x32_f16(k1, qf[qb][1], a, 0, 0, 0);
                // lane holds S[kv0+kb*16+quad*4+r][q0+qb*16+l15], r=0..3
                f16x4 pk;
                float acc = 0.f;
                #pragma unroll
                for (int r = 0; r < 4; r++) {
                    float e = __expf(a[r]);
                    float p = (a[r] > tau_eff) ? e : 1.0f;   // gate-off -> exp(0)=1
                    acc += p;
                    pk[r] = (_Float16)p;
                }
                rs[qb] += acc;
                // P row-major [q_local][kv_local], 4 contiguous kv per lane
                *(f16x4*)(pb + (qb * 16 + l15) * PSTRIDE + kb * 16 + quad * 4) = pk;
            }
        }

        // ---- O += P V: A=P (b128 reads), B=Vt (contiguous). Same-wave LDS, no barrier.
        #pragma unroll
        for (int ks = 0; ks < 2; ks++) {
            f16x8 pa[4];
            #pragma unroll
            for (int qb = 0; qb < 4; qb++)
                pa[qb] = *(const f16x8*)(pb + (qb * 16 + l15) * PSTRIDE + ks * 32 + quad * 8);
            #pragma unroll
            for (int db = 0; db < 4; db++) {
                f16x8 vf = *(const f16x8*)(Vb + (db * 16 + l15) * SEQ + kv0 + ks * 32 + quad * 8);
                #pragma unroll
                for (int qb = 0; qb < 4; qb++)
                    O[qb][db] = __builtin_amdgcn_mfma_f32_16x16x32_f16(pa[qb], vf, O[qb][db], 0, 0, 0);
            }
        }
    }

    // ---- cross-wave reduction: symmetric exchange through the dead P-buffers.
    // Wave w owns qb = {2w, 2w+1}. Each wave writes its partials for the qbs the
    // OTHER wave owns into its OWN region (2048 floats O + 128 floats rs <= 9216 B).
    __syncthreads();   // drains main-loop LDS traffic before overlay reuse
    const int oth = 1 - wave;
    float* xw = (float*)(pbuf + wave * (64 * PSTRIDE));
    #pragma unroll
    for (int qh = 0; qh < 2; qh++) {
        const int qb = oth * 2 + qh;
        #pragma unroll
        for (int db = 0; db < 4; db++)
            *(f32x4*)(xw + (qh * 4 + db) * 256 + lane * 4) = O[qb][db];
        xw[2048 + qh * 64 + lane] = rs[qb];
    }
    __syncthreads();
    const float* xr = (const float*)(pbuf + oth * (64 * PSTRIDE));
    #pragma unroll
    for (int qh = 0; qh < 2; qh++) {
        const int qb = wave * 2 + qh;
        #pragma unroll
        for (int db = 0; db < 4; db++) {
            f32x4 t = *(const f32x4*)(xr + (qh * 4 + db) * 256 + lane * 4);
            O[qb][db][0] += t[0]; O[qb][db][1] += t[1];
            O[qb][db][2] += t[2]; O[qb][db][3] += t[3];
        }
        rs[qb] += xr[2048 + qh * 64 + lane];
    }

    // ---- epilogue: finish denominators (sum over kv-quads), store fp32 partials ----
    #pragma unroll
    for (int qh = 0; qh < 2; qh++) {
        const int qb = wave * 2 + qh;
        float v = rs[qb];
        v += __shfl_xor(v, 16);
        v += __shfl_xor(v, 32);
        rs[qb] = v;
    }
    float* Ob = Opart + (size_t)((sp * 8 + bh) * SEQ + q0) * DHEAD;
    #pragma unroll
    for (int qh = 0; qh < 2; qh++) {
        const int qb = wave * 2 + qh;
        #pragma unroll
        for (int db = 0; db < 4; db++)
            #pragma unroll
            for (int r = 0; r < 4; r++)
                Ob[(qb * 16 + quad * 4 + r) * DHEAD + db * 16 + l15] = O[qb][db][r];
    }
    if (quad == 0) {
        #pragma unroll
        for (int qh = 0; qh < 2; qh++) {
            const int qb = wave * 2 + qh;
            lpart[(sp * 8 + bh) * SEQ + q0 + qb * 16 + l15] = rs[qb];
        }
    }
}

// ---------------- Kernel 3: combine split-KV partials ----------------
__global__ __launch_bounds__(256) void sta_combine(
    const float* __restrict__ Opart, const float* __restrict__ lpart,
    _Float16* __restrict__ AO)
{
    const int idx = blockIdx.x * 256 + threadIdx.x;     // 524288
    const int dg = idx & 15, n = (idx >> 4) & (SEQ - 1), bh = idx >> 16;
    const int d0 = dg * 4;
    float4 o = {0.f, 0.f, 0.f, 0.f};
    float l = 0.f;
    #pragma unroll
    for (int s = 0; s < 4; s++) {
        const float4 os = *(const float4*)(Opart + (size_t)((s * 8 + bh) * SEQ + n) * DHEAD + d0);
        o.x += os.x; o.y += os.y; o.z += os.z; o.w += os.w;
        l += lpart[(s * 8 + bh) * SEQ + n];
    }
    const float inv = 1.0f / l;
    const int b = bh >> 2, h = bh & 3;
    f16x4 res;
    res[0] = (_Float16)(o.x * inv); res[1] = (_Float16)(o.y * inv);
    res[2] = (_Float16)(o.z * inv); res[3] = (_Float16)(o.w * inv);
    *(f16x4*)(AO + (size_t)(b * SEQ + n) * CDIM + h * DHEAD + d0) = res;
}

// ---------------- Kernel 4: output projection ----------------
__global__ __launch_bounds__(256) void sta_oproj(
    const _Float16* __restrict__ AO, const _Float16* __restrict__ w16o,
    const float* __restrict__ ob, float* __restrict__ out)
{
    const int wave = threadIdx.x >> 6;
    const int lane = threadIdx.x & 63;
    const int l15  = lane & 15;
    const int quad = lane >> 4;
    const int row0 = blockIdx.x * 64 + wave * 16;
    const int quarter = blockIdx.y;

    f16x8 af[8];
    const _Float16* arow = AO + (row0 + l15) * CDIM + quad * 8;
    #pragma unroll
    for (int ks = 0; ks < 8; ks++) af[ks] = *(const f16x8*)(arow + ks * 32);

    #pragma unroll 1
    for (int ct = 0; ct < 4; ct++) {
        const int ctg = quarter * 4 + ct;
        const _Float16* wr = w16o + (ctg * 16 + l15) * CDIM + quad * 8;
        f32x4 acc = {0.f, 0.f, 0.f, 0.f};
        #pragma unroll
        for (int ks = 0; ks < 8; ks++)
            acc = __builtin_amdgcn_mfma_f32_16x16x32_f16(*(const f16x8*)(wr + ks * 32), af[ks], acc, 0, 0, 0);
        const float4 bv = *(const float4*)(ob + ctg * 16 + quad * 4);
        const int c0 = ctg * 16 + quad * 4;
        float4 res;
        res.x = acc[0] + bv.x; res.y = acc[1] + bv.y;
        res.z = acc[2] + bv.z; res.w = acc[3] + bv.w;
        *(float4*)(out + (size_t)(row0 + l15) * CDIM + c0) = res;
    }
}

extern "C" void kernel_launch(void* const* d_in, const int* in_sizes, int n_in,
                              void* d_out, int out_size, void* d_ws, size_t ws_size,
                              hipStream_t stream) {
    const float* x   = (const float*)d_in[0];
    const float* qw  = (const float*)d_in[1];
    const float* qb  = (const float*)d_in[2];
    const float* kw  = (const float*)d_in[3];
    const float* kb  = (const float*)d_in[4];
    const float* vw  = (const float*)d_in[5];
    const float* vb  = (const float*)d_in[6];
    const float* ow  = (const float*)d_in[7];
    const float* ob  = (const float*)d_in[8];
    const float* tau = (const float*)d_in[9];

    _Float16* w16 = (_Float16*)d_ws;
    _Float16* Q   = w16 + 262144;
    _Float16* K   = Q + 2097152;
    _Float16* Vt  = K + 2097152;
    _Float16* AO  = Vt + 2097152;
    float* Opart  = (float*)(AO + 2097152);
    float* lpart  = Opart + 8388608;

    sta_prep   <<<dim3(32, 4),      256, 0, stream>>>(qw, kw, vw, ow, w16);
    sta_qkv    <<<dim3(128, 3, 2),  256, 0, stream>>>(x, w16, qb, kb, vb, Q, K, Vt);
    sta_attn   <<<dim3(64, 8, 4),   128, 0, stream>>>(Q, K, Vt, tau, Opart, lpart);
    sta_combine<<<2048,             256, 0, stream>>>(Opart, lpart, AO);
    sta_oproj  <<<dim3(128, 4),     256, 0, stream>>>(AO, w16 + 3 * 65536, ob, (float*)d_out);
}

// Round 2
// 261.056 us; speedup vs baseline: 1.6401x; 1.6401x over previous
//
#include <hip/hip_runtime.h>

#define SEQ   4096
#define CDIM  256
#define NHEAD 4
#define DHEAD 64
#define PSTRIDE 72   // P-buffer row stride (f16): 144 B rows -> 16B-aligned b128 reads

typedef float    f32x4 __attribute__((ext_vector_type(4)));
typedef _Float16 f16x8 __attribute__((ext_vector_type(8)));
typedef _Float16 f16x4 __attribute__((ext_vector_type(4)));

__device__ __forceinline__ f16x8 cvt_frag(const float* __restrict__ p) {
    float4 f0 = *(const float4*)p;
    float4 f1 = *(const float4*)(p + 4);
    f16x8 r;
    r[0]=(_Float16)f0.x; r[1]=(_Float16)f0.y; r[2]=(_Float16)f0.z; r[3]=(_Float16)f0.w;
    r[4]=(_Float16)f1.x; r[5]=(_Float16)f1.y; r[6]=(_Float16)f1.z; r[7]=(_Float16)f1.w;
    return r;
}

// ---------------- Kernel 0: weight fp32->fp16 prep ----------------
__global__ __launch_bounds__(256) void sta_prep(
    const float* __restrict__ qw, const float* __restrict__ kw,
    const float* __restrict__ vw, const float* __restrict__ ow,
    _Float16* __restrict__ w16)
{
    const int mat = blockIdx.y;
    const float* src = (mat == 0) ? qw : (mat == 1) ? kw : (mat == 2) ? vw : ow;
    const int i = (blockIdx.x * 256 + threadIdx.x) * 8;
    *(f16x8*)(w16 + mat * 65536 + i) = cvt_frag(src + i);
}

// ---------------- Kernel 1: QKV projection ----------------
__global__ __launch_bounds__(256) void sta_qkv(
    const float* __restrict__ x, const _Float16* __restrict__ w16,
    const float* __restrict__ qb, const float* __restrict__ kb, const float* __restrict__ vb,
    _Float16* __restrict__ Qo, _Float16* __restrict__ Ko, _Float16* __restrict__ Vo)
{
    const int wave = threadIdx.x >> 6;
    const int lane = threadIdx.x & 63;
    const int l15  = lane & 15;
    const int quad = lane >> 4;
    const int mat  = blockIdx.y;
    const int half = blockIdx.z;
    const int row0 = blockIdx.x * 64 + wave * 16;

    const _Float16* w    = w16 + mat * 65536;
    const float*    bias = (mat == 0) ? qb : (mat == 1) ? kb : vb;

    f16x8 xf[8];
    const float* xrow = x + (row0 + l15) * CDIM + quad * 8;
    #pragma unroll
    for (int ks = 0; ks < 8; ks++) xf[ks] = cvt_frag(xrow + ks * 32);

    #pragma unroll 1
    for (int ct = 0; ct < 8; ct++) {
        const int ctg = half * 8 + ct;
        const _Float16* wr = w + (ctg * 16 + l15) * CDIM + quad * 8;
        f32x4 acc = {0.f, 0.f, 0.f, 0.f};
        if (mat < 2) {
            #pragma unroll
            for (int ks = 0; ks < 8; ks++)
                acc = __builtin_amdgcn_mfma_f32_16x16x32_f16(*(const f16x8*)(wr + ks * 32), xf[ks], acc, 0, 0, 0);
            const float4 bv = *(const float4*)(bias + ctg * 16 + quad * 4);
            const int c0 = ctg * 16 + quad * 4;
            const int h = c0 >> 6, d0 = c0 & 63;
            const int grow = row0 + l15, b = grow >> 12, n = grow & (SEQ - 1);
            const float sc = (mat == 0) ? 0.0625f : 1.0f;
            f16x4 o;
            o[0] = (_Float16)((acc[0] + bv.x) * sc);
            o[1] = (_Float16)((acc[1] + bv.y) * sc);
            o[2] = (_Float16)((acc[2] + bv.z) * sc);
            o[3] = (_Float16)((acc[3] + bv.w) * sc);
            _Float16* dst = ((mat == 0) ? Qo : Ko) + (((b * NHEAD + h) * SEQ + n) * DHEAD + d0);
            *(f16x4*)dst = o;
        } else {
            #pragma unroll
            for (int ks = 0; ks < 8; ks++)
                acc = __builtin_amdgcn_mfma_f32_16x16x32_f16(xf[ks], *(const f16x8*)(wr + ks * 32), acc, 0, 0, 0);
            const int c = ctg * 16 + l15;
            const int h = c >> 6, d = c & 63;
            const float bv = bias[c];
            const int grow0 = row0 + quad * 4, b = grow0 >> 12, n0 = grow0 & (SEQ - 1);
            f16x4 o;
            #pragma unroll
            for (int r = 0; r < 4; r++) o[r] = (_Float16)(acc[r] + bv);
            *(f16x4*)(Vo + (((b * NHEAD + h) * DHEAD + d) * SEQ + n0)) = o;
        }
    }
}

// ---------------- Kernel 2: flash attention, 2-wave blocks, in-block kv split ----------------
// grid (64 q-tiles of 64, 8 bh, 4 kv-splits), 128 thr = 2 waves.
// Each wave owns 64 Q-rows x 8 kv-tiles (half the block's kv range) with a
// wave-private P-buffer (no barriers in the sweep). QK^T operand-swapped:
// S[kv][q] -> packed ds_write_b64 of P; PV reads P back as b128 A-fragments.
// Epilogue: symmetric cross-wave O/denominator exchange through the (dead)
// P-buffers, each wave finishes + stores its 32 owned Q-rows.
// NOTE launch bound: (128, 2) NOT (128, 4) — the latter empirically caps VGPR
// at 64 (not 128) and spills the O accumulator to scratch: 826 MB of HBM
// writes, 3.4x regression (round-1 post-mortem).
__global__ __launch_bounds__(128, 2) void sta_attn(
    const _Float16* __restrict__ Q, const _Float16* __restrict__ K, const _Float16* __restrict__ Vt,
    const float* __restrict__ taup,
    float* __restrict__ Opart, float* __restrict__ lpart)
{
    __shared__ __align__(16) _Float16 pbuf[2 * 64 * PSTRIDE];   // per-wave halves

    const int wave = threadIdx.x >> 6;
    const int lane = threadIdx.x & 63;
    const int l15  = lane & 15;
    const int quad = lane >> 4;
    const int qt = blockIdx.x;   // 0..63
    const int bh = blockIdx.y;   // 0..7
    const int sp = blockIdx.z;   // 0..3
    const float tau_eff = fmaxf(taup[0], 0.0f);

    _Float16* pb = pbuf + wave * (64 * PSTRIDE);   // wave-private P-buffer

    const _Float16* Qb = Q  + bh * SEQ * DHEAD;
    const _Float16* Kb = K  + bh * SEQ * DHEAD;
    const _Float16* Vb = Vt + bh * DHEAD * SEQ;

    const int q0 = qt * 64;

    // Q B-fragments, held for the whole sweep: col=l15 -> q, k=quad*8+j -> d
    f16x8 qf[4][2];
    #pragma unroll
    for (int qb = 0; qb < 4; qb++)
        #pragma unroll
        for (int ks = 0; ks < 2; ks++)
            qf[qb][ks] = *(const f16x8*)(Qb + (q0 + qb * 16 + l15) * DHEAD + ks * 32 + quad * 8);

    f32x4 O[4][4];   // [qb][db]
    #pragma unroll
    for (int qb = 0; qb < 4; qb++)
        #pragma unroll
        for (int db = 0; db < 4; db++) O[qb][db] = (f32x4){0.f, 0.f, 0.f, 0.f};
    float rs[4] = {0.f, 0.f, 0.f, 0.f};   // per-lane denominator partials, q = q0+qb*16+l15

    const int kt0 = sp * 16 + wave * 8;   // this wave's 8 kv-tiles
    #pragma unroll 1
    for (int kt = kt0; kt < kt0 + 8; kt++) {
        const int kv0 = kt * 64;

        // ---- S' = K Q^T (swapped): rows=kv, cols=q. Gate+exp, packed b64 P-writes.
        #pragma unroll
        for (int kb = 0; kb < 4; kb++) {
            const _Float16* kp = Kb + (kv0 + kb * 16 + l15) * DHEAD + quad * 8;
            f16x8 k0 = *(const f16x8*)kp;
            f16x8 k1 = *(const f16x8*)(kp + 32);
            #pragma unroll
            for (int qb = 0; qb < 4; qb++) {
                f32x4 a = {0.f, 0.f, 0.f, 0.f};
                a = __builtin_amdgcn_mfma_f32_16x16x32_f16(k0, qf[qb][0], a, 0, 0, 0);
                a = __builtin_amdgcn_mfma_f32_16x16x32_f16(k1, qf[qb][1], a, 0, 0, 0);
                // lane holds S[kv0+kb*16+quad*4+r][q0+qb*16+l15], r=0..3
                f16x4 pk;
                float acc = 0.f;
                #pragma unroll
                for (int r = 0; r < 4; r++) {
                    float e = __expf(a[r]);
                    float p = (a[r] > tau_eff) ? e : 1.0f;   // gate-off -> exp(0)=1
                    acc += p;
                    pk[r] = (_Float16)p;
                }
                rs[qb] += acc;
                // P row-major [q_local][kv_local], 4 contiguous kv per lane
                *(f16x4*)(pb + (qb * 16 + l15) * PSTRIDE + kb * 16 + quad * 4) = pk;
            }
        }

        // ---- O += P V: A=P (b128 reads), B=Vt (contiguous). Same-wave LDS, no barrier.
        #pragma unroll
        for (int ks = 0; ks < 2; ks++) {
            f16x8 pa[4];
            #pragma unroll
            for (int qb = 0; qb < 4; qb++)
                pa[qb] = *(const f16x8*)(pb + (qb * 16 + l15) * PSTRIDE + ks * 32 + quad * 8);
            #pragma unroll
            for (int db = 0; db < 4; db++) {
                f16x8 vf = *(const f16x8*)(Vb + (db * 16 + l15) * SEQ + kv0 + ks * 32 + quad * 8);
                #pragma unroll
                for (int qb = 0; qb < 4; qb++)
                    O[qb][db] = __builtin_amdgcn_mfma_f32_16x16x32_f16(pa[qb], vf, O[qb][db], 0, 0, 0);
            }
        }
    }

    // ---- cross-wave reduction: symmetric exchange through the dead P-buffers.
    // Wave w owns qb = {2w, 2w+1}. Each wave writes its partials for the qbs the
    // OTHER wave owns into its OWN region (2048 floats O + 128 floats rs <= 9216 B).
    __syncthreads();   // drains main-loop LDS traffic before overlay reuse
    const int oth = 1 - wave;
    float* xw = (float*)(pbuf + wave * (64 * PSTRIDE));
    #pragma unroll
    for (int qh = 0; qh < 2; qh++) {
        const int qb = oth * 2 + qh;
        #pragma unroll
        for (int db = 0; db < 4; db++)
            *(f32x4*)(xw + (qh * 4 + db) * 256 + lane * 4) = O[qb][db];
        xw[2048 + qh * 64 + lane] = rs[qb];
    }
    __syncthreads();
    const float* xr = (const float*)(pbuf + oth * (64 * PSTRIDE));
    #pragma unroll
    for (int qh = 0; qh < 2; qh++) {
        const int qb = wave * 2 + qh;
        #pragma unroll
        for (int db = 0; db < 4; db++) {
            f32x4 t = *(const f32x4*)(xr + (qh * 4 + db) * 256 + lane * 4);
            O[qb][db][0] += t[0]; O[qb][db][1] += t[1];
            O[qb][db][2] += t[2]; O[qb][db][3] += t[3];
        }
        rs[qb] += xr[2048 + qh * 64 + lane];
    }

    // ---- epilogue: finish denominators (sum over kv-quads), store fp32 partials ----
    #pragma unroll
    for (int qh = 0; qh < 2; qh++) {
        const int qb = wave * 2 + qh;
        float v = rs[qb];
        v += __shfl_xor(v, 16);
        v += __shfl_xor(v, 32);
        rs[qb] = v;
    }
    float* Ob = Opart + (size_t)((sp * 8 + bh) * SEQ + q0) * DHEAD;
    #pragma unroll
    for (int qh = 0; qh < 2; qh++) {
        const int qb = wave * 2 + qh;
        #pragma unroll
        for (int db = 0; db < 4; db++)
            #pragma unroll
            for (int r = 0; r < 4; r++)
                Ob[(qb * 16 + quad * 4 + r) * DHEAD + db * 16 + l15] = O[qb][db][r];
    }
    if (quad == 0) {
        #pragma unroll
        for (int qh = 0; qh < 2; qh++) {
            const int qb = wave * 2 + qh;
            lpart[(sp * 8 + bh) * SEQ + q0 + qb * 16 + l15] = rs[qb];
        }
    }
}

// ---------------- Kernel 3: combine split-KV partials ----------------
__global__ __launch_bounds__(256) void sta_combine(
    const float* __restrict__ Opart, const float* __restrict__ lpart,
    _Float16* __restrict__ AO)
{
    const int idx = blockIdx.x * 256 + threadIdx.x;     // 524288
    const int dg = idx & 15, n = (idx >> 4) & (SEQ - 1), bh = idx >> 16;
    const int d0 = dg * 4;
    float4 o = {0.f, 0.f, 0.f, 0.f};
    float l = 0.f;
    #pragma unroll
    for (int s = 0; s < 4; s++) {
        const float4 os = *(const float4*)(Opart + (size_t)((s * 8 + bh) * SEQ + n) * DHEAD + d0);
        o.x += os.x; o.y += os.y; o.z += os.z; o.w += os.w;
        l += lpart[(s * 8 + bh) * SEQ + n];
    }
    const float inv = 1.0f / l;
    const int b = bh >> 2, h = bh & 3;
    f16x4 res;
    res[0] = (_Float16)(o.x * inv); res[1] = (_Float16)(o.y * inv);
    res[2] = (_Float16)(o.z * inv); res[3] = (_Float16)(o.w * inv);
    *(f16x4*)(AO + (size_t)(b * SEQ + n) * CDIM + h * DHEAD + d0) = res;
}

// ---------------- Kernel 4: output projection ----------------
__global__ __launch_bounds__(256) void sta_oproj(
    const _Float16* __restrict__ AO, const _Float16* __restrict__ w16o,
    const float* __restrict__ ob, float* __restrict__ out)
{
    const int wave = threadIdx.x >> 6;
    const int lane = threadIdx.x & 63;
    const int l15  = lane & 15;
    const int quad = lane >> 4;
    const int row0 = blockIdx.x * 64 + wave * 16;
    const int quarter = blockIdx.y;

    f16x8 af[8];
    const _Float16* arow = AO + (row0 + l15) * CDIM + quad * 8;
    #pragma unroll
    for (int ks = 0; ks < 8; ks++) af[ks] = *(const f16x8*)(arow + ks * 32);

    #pragma unroll 1
    for (int ct = 0; ct < 4; ct++) {
        const int ctg = quarter * 4 + ct;
        const _Float16* wr = w16o + (ctg * 16 + l15) * CDIM + quad * 8;
        f32x4 acc = {0.f, 0.f, 0.f, 0.f};
        #pragma unroll
        for (int ks = 0; ks < 8; ks++)
            acc = __builtin_amdgcn_mfma_f32_16x16x32_f16(*(const f16x8*)(wr + ks * 32), af[ks], acc, 0, 0, 0);
        const float4 bv = *(const float4*)(ob + ctg * 16 + quad * 4);
        const int c0 = ctg * 16 + quad * 4;
        float4 res;
        res.x = acc[0] + bv.x; res.y = acc[1] + bv.y;
        res.z = acc[2] + bv.z; res.w = acc[3] + bv.w;
        *(float4*)(out + (size_t)(row0 + l15) * CDIM + c0) = res;
    }
}

extern "C" void kernel_launch(void* const* d_in, const int* in_sizes, int n_in,
                              void* d_out, int out_size, void* d_ws, size_t ws_size,
                              hipStream_t stream) {
    const float* x   = (const float*)d_in[0];
    const float* qw  = (const float*)d_in[1];
    const float* qb  = (const float*)d_in[2];
    const float* kw  = (const float*)d_in[3];
    const float* kb  = (const float*)d_in[4];
    const float* vw  = (const float*)d_in[5];
    const float* vb  = (const float*)d_in[6];
    const float* ow  = (const float*)d_in[7];
    const float* ob  = (const float*)d_in[8];
    const float* tau = (const float*)d_in[9];

    _Float16* w16 = (_Float16*)d_ws;
    _Float16* Q   = w16 + 262144;
    _Float16* K   = Q + 2097152;
    _Float16* Vt  = K + 2097152;
    _Float16* AO  = Vt + 2097152;
    float* Opart  = (float*)(AO + 2097152);
    float* lpart  = Opart + 8388608;

    sta_prep   <<<dim3(32, 4),      256, 0, stream>>>(qw, kw, vw, ow, w16);
    sta_qkv    <<<dim3(128, 3, 2),  256, 0, stream>>>(x, w16, qb, kb, vb, Q, K, Vt);
    sta_attn   <<<dim3(64, 8, 4),   128, 0, stream>>>(Q, K, Vt, tau, Opart, lpart);
    sta_combine<<<2048,             256, 0, stream>>>(Opart, lpart, AO);
    sta_oproj  <<<dim3(128, 4),     256, 0, stream>>>(AO, w16 + 3 * 65536, ob, (float*)d_out);
}

// Round 3
// 243.897 us; speedup vs baseline: 1.7555x; 1.0704x over previous
//
#include <hip/hip_runtime.h>

#define SEQ   4096
#define CDIM  256
#define NHEAD 4
#define DHEAD 64
#define PSTRIDE 72   // P-buffer row stride (f16): 144 B rows -> 16B-aligned b128 reads

typedef float    f32x4 __attribute__((ext_vector_type(4)));
typedef _Float16 f16x8 __attribute__((ext_vector_type(8)));
typedef _Float16 f16x4 __attribute__((ext_vector_type(4)));

__device__ __forceinline__ f16x8 cvt_frag(const float* __restrict__ p) {
    float4 f0 = *(const float4*)p;
    float4 f1 = *(const float4*)(p + 4);
    f16x8 r;
    r[0]=(_Float16)f0.x; r[1]=(_Float16)f0.y; r[2]=(_Float16)f0.z; r[3]=(_Float16)f0.w;
    r[4]=(_Float16)f1.x; r[5]=(_Float16)f1.y; r[6]=(_Float16)f1.z; r[7]=(_Float16)f1.w;
    return r;
}

// ---------------- Kernel 0: weight fp32->fp16 prep ----------------
__global__ __launch_bounds__(256) void sta_prep(
    const float* __restrict__ qw, const float* __restrict__ kw,
    const float* __restrict__ vw, const float* __restrict__ ow,
    _Float16* __restrict__ w16)
{
    const int mat = blockIdx.y;
    const float* src = (mat == 0) ? qw : (mat == 1) ? kw : (mat == 2) ? vw : ow;
    const int i = (blockIdx.x * 256 + threadIdx.x) * 8;
    *(f16x8*)(w16 + mat * 65536 + i) = cvt_frag(src + i);
}

// ---------------- Kernel 1: QKV projection ----------------
__global__ __launch_bounds__(256) void sta_qkv(
    const float* __restrict__ x, const _Float16* __restrict__ w16,
    const float* __restrict__ qb, const float* __restrict__ kb, const float* __restrict__ vb,
    _Float16* __restrict__ Qo, _Float16* __restrict__ Ko, _Float16* __restrict__ Vo)
{
    const int wave = threadIdx.x >> 6;
    const int lane = threadIdx.x & 63;
    const int l15  = lane & 15;
    const int quad = lane >> 4;
    const int mat  = blockIdx.y;
    const int half = blockIdx.z;
    const int row0 = blockIdx.x * 64 + wave * 16;

    const _Float16* w    = w16 + mat * 65536;
    const float*    bias = (mat == 0) ? qb : (mat == 1) ? kb : vb;

    f16x8 xf[8];
    const float* xrow = x + (row0 + l15) * CDIM + quad * 8;
    #pragma unroll
    for (int ks = 0; ks < 8; ks++) xf[ks] = cvt_frag(xrow + ks * 32);

    #pragma unroll 1
    for (int ct = 0; ct < 8; ct++) {
        const int ctg = half * 8 + ct;
        const _Float16* wr = w + (ctg * 16 + l15) * CDIM + quad * 8;
        f32x4 acc = {0.f, 0.f, 0.f, 0.f};
        if (mat < 2) {
            #pragma unroll
            for (int ks = 0; ks < 8; ks++)
                acc = __builtin_amdgcn_mfma_f32_16x16x32_f16(*(const f16x8*)(wr + ks * 32), xf[ks], acc, 0, 0, 0);
            const float4 bv = *(const float4*)(bias + ctg * 16 + quad * 4);
            const int c0 = ctg * 16 + quad * 4;
            const int h = c0 >> 6, d0 = c0 & 63;
            const int grow = row0 + l15, b = grow >> 12, n = grow & (SEQ - 1);
            const float sc = (mat == 0) ? 0.0625f : 1.0f;
            f16x4 o;
            o[0] = (_Float16)((acc[0] + bv.x) * sc);
            o[1] = (_Float16)((acc[1] + bv.y) * sc);
            o[2] = (_Float16)((acc[2] + bv.z) * sc);
            o[3] = (_Float16)((acc[3] + bv.w) * sc);
            _Float16* dst = ((mat == 0) ? Qo : Ko) + (((b * NHEAD + h) * SEQ + n) * DHEAD + d0);
            *(f16x4*)dst = o;
        } else {
            #pragma unroll
            for (int ks = 0; ks < 8; ks++)
                acc = __builtin_amdgcn_mfma_f32_16x16x32_f16(xf[ks], *(const f16x8*)(wr + ks * 32), acc, 0, 0, 0);
            const int c = ctg * 16 + l15;
            const int h = c >> 6, d = c & 63;
            const float bv = bias[c];
            const int grow0 = row0 + quad * 4, b = grow0 >> 12, n0 = grow0 & (SEQ - 1);
            f16x4 o;
            #pragma unroll
            for (int r = 0; r < 4; r++) o[r] = (_Float16)(acc[r] + bv);
            *(f16x4*)(Vo + (((b * NHEAD + h) * DHEAD + d) * SEQ + n0)) = o;
        }
    }
}

// ---------------- Kernel 2: flash attention, slim 1-wave blocks ----------------
// grid (128 q-tiles of 32, 8 bh, 4 kv-splits) = 4096 one-wave blocks
// -> 16 waves/CU (4/SIMD grid cap; also the 16-workgroup/CU cap), vs 2/SIMD
// with the old 64-row tiles. Per-wave regs SHRINK (O: 32 acc, qf: 16), so
// no spill risk. The dominant VALU (gate+exp) scales with S-elements, i.e.
// with MFMA count, so per-MFMA overhead is nearly unchanged; only K/V load
// amortization halves (cheap b128 loads).
// NOTE: multi-wave blocks with a cross-wave O exchange were tried twice
// (rounds 1-2): both produced scratch spill traffic (177-826 MB HBM writes)
// from O live-ranges spanning barriers. Do not revisit without checking
// WRITE_SIZE ~= 33 MB.
__global__ __launch_bounds__(64) void sta_attn(
    const _Float16* __restrict__ Q, const _Float16* __restrict__ K, const _Float16* __restrict__ Vt,
    const float* __restrict__ taup,
    float* __restrict__ Opart, float* __restrict__ lpart)
{
    __shared__ __align__(16) _Float16 pbuf[32 * PSTRIDE];   // wave-private, no barriers

    const int lane = threadIdx.x;
    const int l15  = lane & 15;
    const int quad = lane >> 4;
    const int qt = blockIdx.x;   // 0..127
    const int bh = blockIdx.y;   // 0..7
    const int sp = blockIdx.z;   // 0..3
    const float tau_eff = fmaxf(taup[0], 0.0f);

    const _Float16* Qb = Q  + bh * SEQ * DHEAD;
    const _Float16* Kb = K  + bh * SEQ * DHEAD;
    const _Float16* Vb = Vt + bh * DHEAD * SEQ;

    const int q0 = qt * 32;

    // Q B-fragments, held for the whole sweep: col=l15 -> q, k=quad*8+j -> d
    f16x8 qf[2][2];
    #pragma unroll
    for (int qb = 0; qb < 2; qb++)
        #pragma unroll
        for (int ks = 0; ks < 2; ks++)
            qf[qb][ks] = *(const f16x8*)(Qb + (q0 + qb * 16 + l15) * DHEAD + ks * 32 + quad * 8);

    f32x4 O[2][4];   // [qb][db]
    #pragma unroll
    for (int qb = 0; qb < 2; qb++)
        #pragma unroll
        for (int db = 0; db < 4; db++) O[qb][db] = (f32x4){0.f, 0.f, 0.f, 0.f};
    float rs[2] = {0.f, 0.f};   // per-lane denominator partials, q = q0+qb*16+l15

    #pragma unroll 1
    for (int kt = sp * 16; kt < sp * 16 + 16; kt++) {
        const int kv0 = kt * 64;

        // ---- S' = K Q^T (swapped): rows=kv, cols=q. Gate+exp, packed b64 P-writes.
        #pragma unroll
        for (int kb = 0; kb < 4; kb++) {
            const _Float16* kp = Kb + (kv0 + kb * 16 + l15) * DHEAD + quad * 8;
            f16x8 k0 = *(const f16x8*)kp;
            f16x8 k1 = *(const f16x8*)(kp + 32);
            #pragma unroll
            for (int qb = 0; qb < 2; qb++) {
                f32x4 a = {0.f, 0.f, 0.f, 0.f};
                a = __builtin_amdgcn_mfma_f32_16x16x32_f16(k0, qf[qb][0], a, 0, 0, 0);
                a = __builtin_amdgcn_mfma_f32_16x16x32_f16(k1, qf[qb][1], a, 0, 0, 0);
                // lane holds S[kv0+kb*16+quad*4+r][q0+qb*16+l15], r=0..3
                f16x4 pk;
                float acc = 0.f;
                #pragma unroll
                for (int r = 0; r < 4; r++) {
                    float e = __expf(a[r]);
                    float p = (a[r] > tau_eff) ? e : 1.0f;   // gate-off -> exp(0)=1
                    acc += p;
                    pk[r] = (_Float16)p;
                }
                rs[qb] += acc;
                // P row-major [q_local][kv_local], 4 contiguous kv per lane
                *(f16x4*)(pbuf + (qb * 16 + l15) * PSTRIDE + kb * 16 + quad * 4) = pk;
            }
        }

        // ---- O += P V: A=P (b128 reads), B=Vt (contiguous). Same-wave LDS, no barrier.
        #pragma unroll
        for (int ks = 0; ks < 2; ks++) {
            f16x8 pa[2];
            #pragma unroll
            for (int qb = 0; qb < 2; qb++)
                pa[qb] = *(const f16x8*)(pbuf + (qb * 16 + l15) * PSTRIDE + ks * 32 + quad * 8);
            #pragma unroll
            for (int db = 0; db < 4; db++) {
                f16x8 vf = *(const f16x8*)(Vb + (db * 16 + l15) * SEQ + kv0 + ks * 32 + quad * 8);
                #pragma unroll
                for (int qb = 0; qb < 2; qb++)
                    O[qb][db] = __builtin_amdgcn_mfma_f32_16x16x32_f16(pa[qb], vf, O[qb][db], 0, 0, 0);
            }
        }
    }

    // ---- epilogue: finish denominators (sum over kv-quads), store fp32 partials ----
    #pragma unroll
    for (int qb = 0; qb < 2; qb++) {
        float v = rs[qb];
        v += __shfl_xor(v, 16);
        v += __shfl_xor(v, 32);
        rs[qb] = v;
    }
    float* Ob = Opart + (size_t)((sp * 8 + bh) * SEQ + q0) * DHEAD;
    #pragma unroll
    for (int qb = 0; qb < 2; qb++)
        #pragma unroll
        for (int db = 0; db < 4; db++)
            #pragma unroll
            for (int r = 0; r < 4; r++)
                Ob[(qb * 16 + quad * 4 + r) * DHEAD + db * 16 + l15] = O[qb][db][r];
    if (quad == 0) {
        #pragma unroll
        for (int qb = 0; qb < 2; qb++)
            lpart[(sp * 8 + bh) * SEQ + q0 + qb * 16 + l15] = rs[qb];
    }
}

// ---------------- Kernel 3: combine split-KV partials ----------------
__global__ __launch_bounds__(256) void sta_combine(
    const float* __restrict__ Opart, const float* __restrict__ lpart,
    _Float16* __restrict__ AO)
{
    const int idx = blockIdx.x * 256 + threadIdx.x;     // 524288
    const int dg = idx & 15, n = (idx >> 4) & (SEQ - 1), bh = idx >> 16;
    const int d0 = dg * 4;
    float4 o = {0.f, 0.f, 0.f, 0.f};
    float l = 0.f;
    #pragma unroll
    for (int s = 0; s < 4; s++) {
        const float4 os = *(const float4*)(Opart + (size_t)((s * 8 + bh) * SEQ + n) * DHEAD + d0);
        o.x += os.x; o.y += os.y; o.z += os.z; o.w += os.w;
        l += lpart[(s * 8 + bh) * SEQ + n];
    }
    const float inv = 1.0f / l;
    const int b = bh >> 2, h = bh & 3;
    f16x4 res;
    res[0] = (_Float16)(o.x * inv); res[1] = (_Float16)(o.y * inv);
    res[2] = (_Float16)(o.z * inv); res[3] = (_Float16)(o.w * inv);
    *(f16x4*)(AO + (size_t)(b * SEQ + n) * CDIM + h * DHEAD + d0) = res;
}

// ---------------- Kernel 4: output projection ----------------
__global__ __launch_bounds__(256) void sta_oproj(
    const _Float16* __restrict__ AO, const _Float16* __restrict__ w16o,
    const float* __restrict__ ob, float* __restrict__ out)
{
    const int wave = threadIdx.x >> 6;
    const int lane = threadIdx.x & 63;
    const int l15  = lane & 15;
    const int quad = lane >> 4;
    const int row0 = blockIdx.x * 64 + wave * 16;
    const int quarter = blockIdx.y;

    f16x8 af[8];
    const _Float16* arow = AO + (row0 + l15) * CDIM + quad * 8;
    #pragma unroll
    for (int ks = 0; ks < 8; ks++) af[ks] = *(const f16x8*)(arow + ks * 32);

    #pragma unroll 1
    for (int ct = 0; ct < 4; ct++) {
        const int ctg = quarter * 4 + ct;
        const _Float16* wr = w16o + (ctg * 16 + l15) * CDIM + quad * 8;
        f32x4 acc = {0.f, 0.f, 0.f, 0.f};
        #pragma unroll
        for (int ks = 0; ks < 8; ks++)
            acc = __builtin_amdgcn_mfma_f32_16x16x32_f16(*(const f16x8*)(wr + ks * 32), af[ks], acc, 0, 0, 0);
        const float4 bv = *(const float4*)(ob + ctg * 16 + quad * 4);
        const int c0 = ctg * 16 + quad * 4;
        float4 res;
        res.x = acc[0] + bv.x; res.y = acc[1] + bv.y;
        res.z = acc[2] + bv.z; res.w = acc[3] + bv.w;
        *(float4*)(out + (size_t)(row0 + l15) * CDIM + c0) = res;
    }
}

extern "C" void kernel_launch(void* const* d_in, const int* in_sizes, int n_in,
                              void* d_out, int out_size, void* d_ws, size_t ws_size,
                              hipStream_t stream) {
    const float* x   = (const float*)d_in[0];
    const float* qw  = (const float*)d_in[1];
    const float* qb  = (const float*)d_in[2];
    const float* kw  = (const float*)d_in[3];
    const float* kb  = (const float*)d_in[4];
    const float* vw  = (const float*)d_in[5];
    const float* vb  = (const float*)d_in[6];
    const float* ow  = (const float*)d_in[7];
    const float* ob  = (const float*)d_in[8];
    const float* tau = (const float*)d_in[9];

    _Float16* w16 = (_Float16*)d_ws;
    _Float16* Q   = w16 + 262144;
    _Float16* K   = Q + 2097152;
    _Float16* Vt  = K + 2097152;
    _Float16* AO  = Vt + 2097152;
    float* Opart  = (float*)(AO + 2097152);
    float* lpart  = Opart + 8388608;

    sta_prep   <<<dim3(32, 4),      256, 0, stream>>>(qw, kw, vw, ow, w16);
    sta_qkv    <<<dim3(128, 3, 2),  256, 0, stream>>>(x, w16, qb, kb, vb, Q, K, Vt);
    sta_attn   <<<dim3(128, 8, 4),   64, 0, stream>>>(Q, K, Vt, tau, Opart, lpart);
    sta_combine<<<2048,             256, 0, stream>>>(Opart, lpart, AO);
    sta_oproj  <<<dim3(128, 4),     256, 0, stream>>>(AO, w16 + 3 * 65536, ob, (float*)d_out);
}

// Round 4
// 216.990 us; speedup vs baseline: 1.9732x; 1.1240x over previous
//
#include <hip/hip_runtime.h>

#define SEQ   4096
#define CDIM  256
#define NHEAD 4
#define DHEAD 64
#define PSTRIDE 72   // P-buffer row stride (f16): 144 B rows -> 16B-aligned b128 reads

typedef float    f32x4 __attribute__((ext_vector_type(4)));
typedef _Float16 f16x8 __attribute__((ext_vector_type(8)));
typedef _Float16 f16x4 __attribute__((ext_vector_type(4)));

__device__ __forceinline__ f16x8 cvt_frag(const float* __restrict__ p) {
    float4 f0 = *(const float4*)p;
    float4 f1 = *(const float4*)(p + 4);
    f16x8 r;
    r[0]=(_Float16)f0.x; r[1]=(_Float16)f0.y; r[2]=(_Float16)f0.z; r[3]=(_Float16)f0.w;
    r[4]=(_Float16)f1.x; r[5]=(_Float16)f1.y; r[6]=(_Float16)f1.z; r[7]=(_Float16)f1.w;
    return r;
}

// ---------------- Kernel 0: weight fp32->fp16 prep ----------------
__global__ __launch_bounds__(256) void sta_prep(
    const float* __restrict__ qw, const float* __restrict__ kw,
    const float* __restrict__ vw, const float* __restrict__ ow,
    _Float16* __restrict__ w16)
{
    const int mat = blockIdx.y;
    const float* src = (mat == 0) ? qw : (mat == 1) ? kw : (mat == 2) ? vw : ow;
    const int i = (blockIdx.x * 256 + threadIdx.x) * 8;
    *(f16x8*)(w16 + mat * 65536 + i) = cvt_frag(src + i);
}

// ---------------- Kernel 1: QKV projection ----------------
__global__ __launch_bounds__(256) void sta_qkv(
    const float* __restrict__ x, const _Float16* __restrict__ w16,
    const float* __restrict__ qb, const float* __restrict__ kb, const float* __restrict__ vb,
    _Float16* __restrict__ Qo, _Float16* __restrict__ Ko, _Float16* __restrict__ Vo)
{
    const int wave = threadIdx.x >> 6;
    const int lane = threadIdx.x & 63;
    const int l15  = lane & 15;
    const int quad = lane >> 4;
    const int mat  = blockIdx.y;
    const int half = blockIdx.z;
    const int row0 = blockIdx.x * 64 + wave * 16;

    const _Float16* w    = w16 + mat * 65536;
    const float*    bias = (mat == 0) ? qb : (mat == 1) ? kb : vb;

    f16x8 xf[8];
    const float* xrow = x + (row0 + l15) * CDIM + quad * 8;
    #pragma unroll
    for (int ks = 0; ks < 8; ks++) xf[ks] = cvt_frag(xrow + ks * 32);

    #pragma unroll 1
    for (int ct = 0; ct < 8; ct++) {
        const int ctg = half * 8 + ct;
        const _Float16* wr = w + (ctg * 16 + l15) * CDIM + quad * 8;
        f32x4 acc = {0.f, 0.f, 0.f, 0.f};
        if (mat < 2) {
            #pragma unroll
            for (int ks = 0; ks < 8; ks++)
                acc = __builtin_amdgcn_mfma_f32_16x16x32_f16(*(const f16x8*)(wr + ks * 32), xf[ks], acc, 0, 0, 0);
            const float4 bv = *(const float4*)(bias + ctg * 16 + quad * 4);
            const int c0 = ctg * 16 + quad * 4;
            const int h = c0 >> 6, d0 = c0 & 63;
            const int grow = row0 + l15, b = grow >> 12, n = grow & (SEQ - 1);
            const float sc = (mat == 0) ? 0.0625f : 1.0f;
            f16x4 o;
            o[0] = (_Float16)((acc[0] + bv.x) * sc);
            o[1] = (_Float16)((acc[1] + bv.y) * sc);
            o[2] = (_Float16)((acc[2] + bv.z) * sc);
            o[3] = (_Float16)((acc[3] + bv.w) * sc);
            _Float16* dst = ((mat == 0) ? Qo : Ko) + (((b * NHEAD + h) * SEQ + n) * DHEAD + d0);
            *(f16x4*)dst = o;
        } else {
            #pragma unroll
            for (int ks = 0; ks < 8; ks++)
                acc = __builtin_amdgcn_mfma_f32_16x16x32_f16(xf[ks], *(const f16x8*)(wr + ks * 32), acc, 0, 0, 0);
            const int c = ctg * 16 + l15;
            const int h = c >> 6, d = c & 63;
            const float bv = bias[c];
            const int grow0 = row0 + quad * 4, b = grow0 >> 12, n0 = grow0 & (SEQ - 1);
            f16x4 o;
            #pragma unroll
            for (int r = 0; r < 4; r++) o[r] = (_Float16)(acc[r] + bv);
            *(f16x4*)(Vo + (((b * NHEAD + h) * DHEAD + d) * SEQ + n0)) = o;
        }
    }
}

// ---------------- Kernel 2: flash attention, fat 1-wave blocks, 8 kv-splits --------
// grid (64 q-tiles of 64, 8 bh, 8 kv-splits of 8 tiles) = 4096 one-wave blocks
// -> 16 waves/CU = 4/SIMD.
// HISTORY (do not regress):
//  - r0: sp=4, fat (qb=4): 91.7 us, occ 20.6% (grid-limited 2/SIMD), stall-heavy.
//  - r1/r2: 2-wave blocks + cross-wave O exchange: O live across barriers ->
//    scratch spills (177-826 MB HBM writes). Dead end.
//  - r3: sp=4, slim (qb=2), 4096 waves: occ 43.8% but 129.7 us. Total busy
//    cycles identical to r0 -> ILP halving (2 indep MFMA/exp/LDS chains vs 4)
//    cancelled the occupancy gain. Per-wave ILP is the binding resource.
//  - r4 (this): 4096 waves at the FAT shape via kv-split 8. Same occupancy as
//    r3, same ILP as r0. Opart doubles to 64 MB (cheap: ~+10 us total).
__global__ __launch_bounds__(64) void sta_attn(
    const _Float16* __restrict__ Q, const _Float16* __restrict__ K, const _Float16* __restrict__ Vt,
    const float* __restrict__ taup,
    float* __restrict__ Opart, float* __restrict__ lpart)
{
    __shared__ __align__(16) _Float16 pbuf[64 * PSTRIDE];   // wave-private, no barriers

    const int lane = threadIdx.x;
    const int l15  = lane & 15;
    const int quad = lane >> 4;
    const int qt = blockIdx.x;   // 0..63
    const int bh = blockIdx.y;   // 0..7
    const int sp = blockIdx.z;   // 0..7
    const float tau_eff = fmaxf(taup[0], 0.0f);

    const _Float16* Qb = Q  + bh * SEQ * DHEAD;
    const _Float16* Kb = K  + bh * SEQ * DHEAD;
    const _Float16* Vb = Vt + bh * DHEAD * SEQ;

    const int q0 = qt * 64;

    // Q B-fragments, held for the whole sweep: col=l15 -> q, k=quad*8+j -> d
    f16x8 qf[4][2];
    #pragma unroll
    for (int qb = 0; qb < 4; qb++)
        #pragma unroll
        for (int ks = 0; ks < 2; ks++)
            qf[qb][ks] = *(const f16x8*)(Qb + (q0 + qb * 16 + l15) * DHEAD + ks * 32 + quad * 8);

    f32x4 O[4][4];   // [qb][db]
    #pragma unroll
    for (int qb = 0; qb < 4; qb++)
        #pragma unroll
        for (int db = 0; db < 4; db++) O[qb][db] = (f32x4){0.f, 0.f, 0.f, 0.f};
    float rs[4] = {0.f, 0.f, 0.f, 0.f};   // per-lane denominator partials, q = q0+qb*16+l15

    #pragma unroll 1
    for (int kt = sp * 8; kt < sp * 8 + 8; kt++) {
        const int kv0 = kt * 64;

        // ---- S' = K Q^T (swapped): rows=kv, cols=q. Gate+exp, packed b64 P-writes.
        #pragma unroll
        for (int kb = 0; kb < 4; kb++) {
            const _Float16* kp = Kb + (kv0 + kb * 16 + l15) * DHEAD + quad * 8;
            f16x8 k0 = *(const f16x8*)kp;
            f16x8 k1 = *(const f16x8*)(kp + 32);
            #pragma unroll
            for (int qb = 0; qb < 4; qb++) {
                f32x4 a = {0.f, 0.f, 0.f, 0.f};
                a = __builtin_amdgcn_mfma_f32_16x16x32_f16(k0, qf[qb][0], a, 0, 0, 0);
                a = __builtin_amdgcn_mfma_f32_16x16x32_f16(k1, qf[qb][1], a, 0, 0, 0);
                // lane holds S[kv0+kb*16+quad*4+r][q0+qb*16+l15], r=0..3
                f16x4 pk;
                float acc = 0.f;
                #pragma unroll
                for (int r = 0; r < 4; r++) {
                    float e = __expf(a[r]);
                    float p = (a[r] > tau_eff) ? e : 1.0f;   // gate-off -> exp(0)=1
                    acc += p;
                    pk[r] = (_Float16)p;
                }
                rs[qb] += acc;
                // P row-major [q_local][kv_local], 4 contiguous kv per lane
                *(f16x4*)(pbuf + (qb * 16 + l15) * PSTRIDE + kb * 16 + quad * 4) = pk;
            }
        }

        // ---- O += P V: A=P (b128 reads), B=Vt (contiguous). Same-wave LDS, no barrier.
        #pragma unroll
        for (int ks = 0; ks < 2; ks++) {
            f16x8 pa[4];
            #pragma unroll
            for (int qb = 0; qb < 4; qb++)
                pa[qb] = *(const f16x8*)(pbuf + (qb * 16 + l15) * PSTRIDE + ks * 32 + quad * 8);
            #pragma unroll
            for (int db = 0; db < 4; db++) {
                f16x8 vf = *(const f16x8*)(Vb + (db * 16 + l15) * SEQ + kv0 + ks * 32 + quad * 8);
                #pragma unroll
                for (int qb = 0; qb < 4; qb++)
                    O[qb][db] = __builtin_amdgcn_mfma_f32_16x16x32_f16(pa[qb], vf, O[qb][db], 0, 0, 0);
            }
        }
    }

    // ---- epilogue: finish denominators (sum over kv-quads), store fp32 partials ----
    #pragma unroll
    for (int qb = 0; qb < 4; qb++) {
        float v = rs[qb];
        v += __shfl_xor(v, 16);
        v += __shfl_xor(v, 32);
        rs[qb] = v;
    }
    float* Ob = Opart + (size_t)((sp * 8 + bh) * SEQ + q0) * DHEAD;
    #pragma unroll
    for (int qb = 0; qb < 4; qb++)
        #pragma unroll
        for (int db = 0; db < 4; db++)
            #pragma unroll
            for (int r = 0; r < 4; r++)
                Ob[(qb * 16 + quad * 4 + r) * DHEAD + db * 16 + l15] = O[qb][db][r];
    if (quad == 0) {
        #pragma unroll
        for (int qb = 0; qb < 4; qb++)
            lpart[(sp * 8 + bh) * SEQ + q0 + qb * 16 + l15] = rs[qb];
    }
}

// ---------------- Kernel 3: combine split-KV partials (8 splits) ----------------
__global__ __launch_bounds__(256) void sta_combine(
    const float* __restrict__ Opart, const float* __restrict__ lpart,
    _Float16* __restrict__ AO)
{
    const int idx = blockIdx.x * 256 + threadIdx.x;     // 524288
    const int dg = idx & 15, n = (idx >> 4) & (SEQ - 1), bh = idx >> 16;
    const int d0 = dg * 4;
    float4 o = {0.f, 0.f, 0.f, 0.f};
    float l = 0.f;
    #pragma unroll
    for (int s = 0; s < 8; s++) {
        const float4 os = *(const float4*)(Opart + (size_t)((s * 8 + bh) * SEQ + n) * DHEAD + d0);
        o.x += os.x; o.y += os.y; o.z += os.z; o.w += os.w;
        l += lpart[(s * 8 + bh) * SEQ + n];
    }
    const float inv = 1.0f / l;
    const int b = bh >> 2, h = bh & 3;
    f16x4 res;
    res[0] = (_Float16)(o.x * inv); res[1] = (_Float16)(o.y * inv);
    res[2] = (_Float16)(o.z * inv); res[3] = (_Float16)(o.w * inv);
    *(f16x4*)(AO + (size_t)(b * SEQ + n) * CDIM + h * DHEAD + d0) = res;
}

// ---------------- Kernel 4: output projection ----------------
__global__ __launch_bounds__(256) void sta_oproj(
    const _Float16* __restrict__ AO, const _Float16* __restrict__ w16o,
    const float* __restrict__ ob, float* __restrict__ out)
{
    const int wave = threadIdx.x >> 6;
    const int lane = threadIdx.x & 63;
    const int l15  = lane & 15;
    const int quad = lane >> 4;
    const int row0 = blockIdx.x * 64 + wave * 16;
    const int quarter = blockIdx.y;

    f16x8 af[8];
    const _Float16* arow = AO + (row0 + l15) * CDIM + quad * 8;
    #pragma unroll
    for (int ks = 0; ks < 8; ks++) af[ks] = *(const f16x8*)(arow + ks * 32);

    #pragma unroll 1
    for (int ct = 0; ct < 4; ct++) {
        const int ctg = quarter * 4 + ct;
        const _Float16* wr = w16o + (ctg * 16 + l15) * CDIM + quad * 8;
        f32x4 acc = {0.f, 0.f, 0.f, 0.f};
        #pragma unroll
        for (int ks = 0; ks < 8; ks++)
            acc = __builtin_amdgcn_mfma_f32_16x16x32_f16(*(const f16x8*)(wr + ks * 32), af[ks], acc, 0, 0, 0);
        const float4 bv = *(const float4*)(ob + ctg * 16 + quad * 4);
        const int c0 = ctg * 16 + quad * 4;
        float4 res;
        res.x = acc[0] + bv.x; res.y = acc[1] + bv.y;
        res.z = acc[2] + bv.z; res.w = acc[3] + bv.w;
        *(float4*)(out + (size_t)(row0 + l15) * CDIM + c0) = res;
    }
}

extern "C" void kernel_launch(void* const* d_in, const int* in_sizes, int n_in,
                              void* d_out, int out_size, void* d_ws, size_t ws_size,
                              hipStream_t stream) {
    const float* x   = (const float*)d_in[0];
    const float* qw  = (const float*)d_in[1];
    const float* qb  = (const float*)d_in[2];
    const float* kw  = (const float*)d_in[3];
    const float* kb  = (const float*)d_in[4];
    const float* vw  = (const float*)d_in[5];
    const float* vb  = (const float*)d_in[6];
    const float* ow  = (const float*)d_in[7];
    const float* ob  = (const float*)d_in[8];
    const float* tau = (const float*)d_in[9];

    _Float16* w16 = (_Float16*)d_ws;
    _Float16* Q   = w16 + 262144;
    _Float16* K   = Q + 2097152;
    _Float16* Vt  = K + 2097152;
    _Float16* AO  = Vt + 2097152;
    float* Opart  = (float*)(AO + 2097152);           // 8 sp x 8 bh x 4096 x 64 f32 = 64 MB
    float* lpart  = Opart + 16777216;                 // 8 sp x 8 bh x 4096 f32 = 1 MB

    sta_prep   <<<dim3(32, 4),      256, 0, stream>>>(qw, kw, vw, ow, w16);
    sta_qkv    <<<dim3(128, 3, 2),  256, 0, stream>>>(x, w16, qb, kb, vb, Q, K, Vt);
    sta_attn   <<<dim3(64, 8, 8),    64, 0, stream>>>(Q, K, Vt, tau, Opart, lpart);
    sta_combine<<<2048,             256, 0, stream>>>(Opart, lpart, AO);
    sta_oproj  <<<dim3(128, 4),     256, 0, stream>>>(AO, w16 + 3 * 65536, ob, (float*)d_out);
}

// Round 6
// 202.018 us; speedup vs baseline: 2.1194x; 1.0741x over previous
//
#include <hip/hip_runtime.h>

#define SEQ   4096
#define CDIM  256
#define NHEAD 4
#define DHEAD 64
#define PSTRIDE 72   // P-buffer row stride (f16): 144 B rows -> 16B-aligned b128 reads
#define LOG2E 1.4426950408889634f

typedef float    f32x4 __attribute__((ext_vector_type(4)));
typedef _Float16 f16x8 __attribute__((ext_vector_type(8)));
typedef _Float16 f16x4 __attribute__((ext_vector_type(4)));
typedef _Float16 f16x2 __attribute__((ext_vector_type(2)));

__device__ __forceinline__ f16x8 cvt_frag(const float* __restrict__ p) {
    float4 f0 = *(const float4*)p;
    float4 f1 = *(const float4*)(p + 4);
    f16x8 r;
    r[0]=(_Float16)f0.x; r[1]=(_Float16)f0.y; r[2]=(_Float16)f0.z; r[3]=(_Float16)f0.w;
    r[4]=(_Float16)f1.x; r[5]=(_Float16)f1.y; r[6]=(_Float16)f1.z; r[7]=(_Float16)f1.w;
    return r;
}

// cvt_pkrtz returns __fp16x2; bit-cast to our _Float16x2 (identical layout).
__device__ __forceinline__ f16x2 pkrtz(float a, float b) {
    return __builtin_bit_cast(f16x2, __builtin_amdgcn_cvt_pkrtz(a, b));
}

// ---------------- Kernel 0: weight fp32->fp16 prep ----------------
__global__ __launch_bounds__(256) void sta_prep(
    const float* __restrict__ qw, const float* __restrict__ kw,
    const float* __restrict__ vw, const float* __restrict__ ow,
    _Float16* __restrict__ w16)
{
    const int mat = blockIdx.y;
    const float* src = (mat == 0) ? qw : (mat == 1) ? kw : (mat == 2) ? vw : ow;
    const int i = (blockIdx.x * 256 + threadIdx.x) * 8;
    *(f16x8*)(w16 + mat * 65536 + i) = cvt_frag(src + i);
}

// ---------------- Kernel 1: QKV projection ----------------
// Q pre-scale folds softmax's base-2 conversion: sc = C^-0.5 * log2(e), so the
// attn kernel's logits are already a*log2e and exp() is a bare v_exp_f32 (2^x).
__global__ __launch_bounds__(256) void sta_qkv(
    const float* __restrict__ x, const _Float16* __restrict__ w16,
    const float* __restrict__ qb, const float* __restrict__ kb, const float* __restrict__ vb,
    _Float16* __restrict__ Qo, _Float16* __restrict__ Ko, _Float16* __restrict__ Vo)
{
    const int wave = threadIdx.x >> 6;
    const int lane = threadIdx.x & 63;
    const int l15  = lane & 15;
    const int quad = lane >> 4;
    const int mat  = blockIdx.y;
    const int half = blockIdx.z;
    const int row0 = blockIdx.x * 64 + wave * 16;

    const _Float16* w    = w16 + mat * 65536;
    const float*    bias = (mat == 0) ? qb : (mat == 1) ? kb : vb;

    f16x8 xf[8];
    const float* xrow = x + (row0 + l15) * CDIM + quad * 8;
    #pragma unroll
    for (int ks = 0; ks < 8; ks++) xf[ks] = cvt_frag(xrow + ks * 32);

    #pragma unroll 1
    for (int ct = 0; ct < 8; ct++) {
        const int ctg = half * 8 + ct;
        const _Float16* wr = w + (ctg * 16 + l15) * CDIM + quad * 8;
        f32x4 acc = {0.f, 0.f, 0.f, 0.f};
        if (mat < 2) {
            #pragma unroll
            for (int ks = 0; ks < 8; ks++)
                acc = __builtin_amdgcn_mfma_f32_16x16x32_f16(*(const f16x8*)(wr + ks * 32), xf[ks], acc, 0, 0, 0);
            const float4 bv = *(const float4*)(bias + ctg * 16 + quad * 4);
            const int c0 = ctg * 16 + quad * 4;
            const int h = c0 >> 6, d0 = c0 & 63;
            const int grow = row0 + l15, b = grow >> 12, n = grow & (SEQ - 1);
            const float sc = (mat == 0) ? (0.0625f * LOG2E) : 1.0f;
            f16x4 o;
            o[0] = (_Float16)((acc[0] + bv.x) * sc);
            o[1] = (_Float16)((acc[1] + bv.y) * sc);
            o[2] = (_Float16)((acc[2] + bv.z) * sc);
            o[3] = (_Float16)((acc[3] + bv.w) * sc);
            _Float16* dst = ((mat == 0) ? Qo : Ko) + (((b * NHEAD + h) * SEQ + n) * DHEAD + d0);
            *(f16x4*)dst = o;
        } else {
            #pragma unroll
            for (int ks = 0; ks < 8; ks++)
                acc = __builtin_amdgcn_mfma_f32_16x16x32_f16(xf[ks], *(const f16x8*)(wr + ks * 32), acc, 0, 0, 0);
            const int c = ctg * 16 + l15;
            const int h = c >> 6, d = c & 63;
            const float bv = bias[c];
            const int grow0 = row0 + quad * 4, b = grow0 >> 12, n0 = grow0 & (SEQ - 1);
            f16x4 o;
            #pragma unroll
            for (int r = 0; r < 4; r++) o[r] = (_Float16)(acc[r] + bv);
            *(f16x4*)(Vo + (((b * NHEAD + h) * DHEAD + d) * SEQ + n0)) = o;
        }
    }
}

// ---------------- Kernel 2: flash attention, fat 1-wave blocks, 6 kv-splits --------
// grid (64 q-tiles of 64, 8 bh, 6 kv-splits of 11/10 tiles) = 3072 one-wave blocks.
// HISTORY (do not regress):
//  - r0: sp=4, fat (qb=4): 91.7 us, occ 20.6% (grid 8/CU), stall-heavy.
//  - r1/r2: 2-wave blocks + cross-wave O exchange -> scratch spills (177-826 MB
//    HBM writes). Dead end.
//  - r3: slim (qb=2): occ 43.8% but 129.7 us; busy cycles identical to r0 ->
//    per-wave ILP (4 indep chains) is a binding resource. Keep qb=4.
//  - r4: sp=8, 4096 waves: occ STUCK at 20.2%, dur 94.5. Register math: 88 arch
//    VGPR + 64 AGPR (O acc) = ~152/wave vs 512/SIMD pool -> 3 waves/SIMD = 12/CU
//    hard cap; grid 16/CU ran as generations 12+4 (avg 8 = r0). REGISTERS, not
//    grid, are the occupancy cap at this shape.
//  - r5 (this): grid = 12/CU exactly (sp=6, sizes 11*4+10*2), single generation,
//    no tail. VALU trims: log2e folded into Q scale (bare v_exp_f32, no mul);
//    cvt_pkrtz packs P pairs (1 op per 2 elems vs cvt+pack chains).
__global__ __launch_bounds__(64) void sta_attn(
    const _Float16* __restrict__ Q, const _Float16* __restrict__ K, const _Float16* __restrict__ Vt,
    const float* __restrict__ taup,
    float* __restrict__ Opart, float* __restrict__ lpart)
{
    __shared__ __align__(16) _Float16 pbuf[64 * PSTRIDE];   // wave-private, no barriers

    const int lane = threadIdx.x;
    const int l15  = lane & 15;
    const int quad = lane >> 4;
    const int qt = blockIdx.x;   // 0..63
    const int bh = blockIdx.y;   // 0..7
    const int sp = blockIdx.z;   // 0..5
    // logits arrive pre-scaled by log2e; scale the gate threshold to match.
    const float tau2 = fmaxf(taup[0], 0.0f) * LOG2E;

    const _Float16* Qb = Q  + bh * SEQ * DHEAD;
    const _Float16* Kb = K  + bh * SEQ * DHEAD;
    const _Float16* Vb = Vt + bh * DHEAD * SEQ;

    const int q0 = qt * 64;

    // Q B-fragments, held for the whole sweep: col=l15 -> q, k=quad*8+j -> d
    f16x8 qf[4][2];
    #pragma unroll
    for (int qb = 0; qb < 4; qb++)
        #pragma unroll
        for (int ks = 0; ks < 2; ks++)
            qf[qb][ks] = *(const f16x8*)(Qb + (q0 + qb * 16 + l15) * DHEAD + ks * 32 + quad * 8);

    f32x4 O[4][4];   // [qb][db]
    #pragma unroll
    for (int qb = 0; qb < 4; qb++)
        #pragma unroll
        for (int db = 0; db < 4; db++) O[qb][db] = (f32x4){0.f, 0.f, 0.f, 0.f};
    float rs[4] = {0.f, 0.f, 0.f, 0.f};   // per-lane denominator partials, q = q0+qb*16+l15

    // kv-split sizes [11,11,11,11,10,10]
    const int kt_beg = sp * 11 - ((sp > 4) ? (sp - 4) : 0);
    const int kt_end = kt_beg + ((sp < 4) ? 11 : 10);
    #pragma unroll 1
    for (int kt = kt_beg; kt < kt_end; kt++) {
        const int kv0 = kt * 64;

        // ---- S' = K Q^T (swapped): rows=kv, cols=q. Gate+exp2, packed b64 P-writes.
        #pragma unroll
        for (int kb = 0; kb < 4; kb++) {
            const _Float16* kp = Kb + (kv0 + kb * 16 + l15) * DHEAD + quad * 8;
            f16x8 k0 = *(const f16x8*)kp;
            f16x8 k1 = *(const f16x8*)(kp + 32);
            #pragma unroll
            for (int qb = 0; qb < 4; qb++) {
                f32x4 a = {0.f, 0.f, 0.f, 0.f};
                a = __builtin_amdgcn_mfma_f32_16x16x32_f16(k0, qf[qb][0], a, 0, 0, 0);
                a = __builtin_amdgcn_mfma_f32_16x16x32_f16(k1, qf[qb][1], a, 0, 0, 0);
                // lane holds S[kv0+kb*16+quad*4+r][q0+qb*16+l15], r=0..3
                float p0 = (a[0] > tau2) ? __builtin_amdgcn_exp2f(a[0]) : 1.0f;
                float p1 = (a[1] > tau2) ? __builtin_amdgcn_exp2f(a[1]) : 1.0f;
                float p2 = (a[2] > tau2) ? __builtin_amdgcn_exp2f(a[2]) : 1.0f;
                float p3 = (a[3] > tau2) ? __builtin_amdgcn_exp2f(a[3]) : 1.0f;
                rs[qb] += (p0 + p1) + (p2 + p3);
                f16x2 lo = pkrtz(p0, p1);
                f16x2 hi = pkrtz(p2, p3);
                f16x4 pk;
                pk[0] = lo[0]; pk[1] = lo[1]; pk[2] = hi[0]; pk[3] = hi[1];
                // P row-major [q_local][kv_local], 4 contiguous kv per lane
                *(f16x4*)(pbuf + (qb * 16 + l15) * PSTRIDE + kb * 16 + quad * 4) = pk;
            }
        }

        // ---- O += P V: A=P (b128 reads), B=Vt (contiguous). Same-wave LDS, no barrier.
        #pragma unroll
        for (int ks = 0; ks < 2; ks++) {
            f16x8 pa[4];
            #pragma unroll
            for (int qb = 0; qb < 4; qb++)
                pa[qb] = *(const f16x8*)(pbuf + (qb * 16 + l15) * PSTRIDE + ks * 32 + quad * 8);
            #pragma unroll
            for (int db = 0; db < 4; db++) {
                f16x8 vf = *(const f16x8*)(Vb + (db * 16 + l15) * SEQ + kv0 + ks * 32 + quad * 8);
                #pragma unroll
                for (int qb = 0; qb < 4; qb++)
                    O[qb][db] = __builtin_amdgcn_mfma_f32_16x16x32_f16(pa[qb], vf, O[qb][db], 0, 0, 0);
            }
        }
    }

    // ---- epilogue: finish denominators (sum over kv-quads), store fp32 partials ----
    #pragma unroll
    for (int qb = 0; qb < 4; qb++) {
        float v = rs[qb];
        v += __shfl_xor(v, 16);
        v += __shfl_xor(v, 32);
        rs[qb] = v;
    }
    float* Ob = Opart + (size_t)((sp * 8 + bh) * SEQ + q0) * DHEAD;
    #pragma unroll
    for (int qb = 0; qb < 4; qb++)
        #pragma unroll
        for (int db = 0; db < 4; db++)
            #pragma unroll
            for (int r = 0; r < 4; r++)
                Ob[(qb * 16 + quad * 4 + r) * DHEAD + db * 16 + l15] = O[qb][db][r];
    if (quad == 0) {
        #pragma unroll
        for (int qb = 0; qb < 4; qb++)
            lpart[(sp * 8 + bh) * SEQ + q0 + qb * 16 + l15] = rs[qb];
    }
}

// ---------------- Kernel 3: combine split-KV partials (6 splits) ----------------
__global__ __launch_bounds__(256) void sta_combine(
    const float* __restrict__ Opart, const float* __restrict__ lpart,
    _Float16* __restrict__ AO)
{
    const int idx = blockIdx.x * 256 + threadIdx.x;     // 524288
    const int dg = idx & 15, n = (idx >> 4) & (SEQ - 1), bh = idx >> 16;
    const int d0 = dg * 4;
    float4 o = {0.f, 0.f, 0.f, 0.f};
    float l = 0.f;
    #pragma unroll
    for (int s = 0; s < 6; s++) {
        const float4 os = *(const float4*)(Opart + (size_t)((s * 8 + bh) * SEQ + n) * DHEAD + d0);
        o.x += os.x; o.y += os.y; o.z += os.z; o.w += os.w;
        l += lpart[(s * 8 + bh) * SEQ + n];
    }
    const float inv = 1.0f / l;
    const int b = bh >> 2, h = bh & 3;
    f16x4 res;
    res[0] = (_Float16)(o.x * inv); res[1] = (_Float16)(o.y * inv);
    res[2] = (_Float16)(o.z * inv); res[3] = (_Float16)(o.w * inv);
    *(f16x4*)(AO + (size_t)(b * SEQ + n) * CDIM + h * DHEAD + d0) = res;
}

// ---------------- Kernel 4: output projection ----------------
__global__ __launch_bounds__(256) void sta_oproj(
    const _Float16* __restrict__ AO, const _Float16* __restrict__ w16o,
    const float* __restrict__ ob, float* __restrict__ out)
{
    const int wave = threadIdx.x >> 6;
    const int lane = threadIdx.x & 63;
    const int l15  = lane & 15;
    const int quad = lane >> 4;
    const int row0 = blockIdx.x * 64 + wave * 16;
    const int quarter = blockIdx.y;

    f16x8 af[8];
    const _Float16* arow = AO + (row0 + l15) * CDIM + quad * 8;
    #pragma unroll
    for (int ks = 0; ks < 8; ks++) af[ks] = *(const f16x8*)(arow + ks * 32);

    #pragma unroll 1
    for (int ct = 0; ct < 4; ct++) {
        const int ctg = quarter * 4 + ct;
        const _Float16* wr = w16o + (ctg * 16 + l15) * CDIM + quad * 8;
        f32x4 acc = {0.f, 0.f, 0.f, 0.f};
        #pragma unroll
        for (int ks = 0; ks < 8; ks++)
            acc = __builtin_amdgcn_mfma_f32_16x16x32_f16(*(const f16x8*)(wr + ks * 32), af[ks], acc, 0, 0, 0);
        const float4 bv = *(const float4*)(ob + ctg * 16 + quad * 4);
        const int c0 = ctg * 16 + quad * 4;
        float4 res;
        res.x = acc[0] + bv.x; res.y = acc[1] + bv.y;
        res.z = acc[2] + bv.z; res.w = acc[3] + bv.w;
        *(float4*)(out + (size_t)(row0 + l15) * CDIM + c0) = res;
    }
}

extern "C" void kernel_launch(void* const* d_in, const int* in_sizes, int n_in,
                              void* d_out, int out_size, void* d_ws, size_t ws_size,
                              hipStream_t stream) {
    const float* x   = (const float*)d_in[0];
    const float* qw  = (const float*)d_in[1];
    const float* qb  = (const float*)d_in[2];
    const float* kw  = (const float*)d_in[3];
    const float* kb  = (const float*)d_in[4];
    const float* vw  = (const float*)d_in[5];
    const float* vb  = (const float*)d_in[6];
    const float* ow  = (const float*)d_in[7];
    const float* ob  = (const float*)d_in[8];
    const float* tau = (const float*)d_in[9];

    _Float16* w16 = (_Float16*)d_ws;
    _Float16* Q   = w16 + 262144;
    _Float16* K   = Q + 2097152;
    _Float16* Vt  = K + 2097152;
    _Float16* AO  = Vt + 2097152;
    float* Opart  = (float*)(AO + 2097152);           // 6 sp x 8 bh x 4096 x 64 f32 = 48 MB
    float* lpart  = Opart + 12582912;                 // 6 sp x 8 bh x 4096 f32

    sta_prep   <<<dim3(32, 4),      256, 0, stream>>>(qw, kw, vw, ow, w16);
    sta_qkv    <<<dim3(128, 3, 2),  256, 0, stream>>>(x, w16, qb, kb, vb, Q, K, Vt);
    sta_attn   <<<dim3(64, 8, 6),    64, 0, stream>>>(Q, K, Vt, tau, Opart, lpart);
    sta_combine<<<2048,             256, 0, stream>>>(Opart, lpart, AO);
    sta_oproj  <<<dim3(128, 4),     256, 0, stream>>>(AO, w16 + 3 * 65536, ob, (float*)d_out);
}